// Round 9
// baseline (336.805 us; speedup 1.0000x reference)
//
#include <hip/hip_runtime.h>

// TableEmbed3D: trilinear grid_sample of a [64, 32,32,32] fp32 table at 1e6
// points, align_corners=False, padding_mode='zeros'.
//
// R13 = R12 resubmit with the only non-standard construct removed:
// __builtin_amdgcn_cvt_f32_ubyte{0..3} replaced by (float)((q>>8k)&0xFF),
// which LLVM pattern-matches to v_cvt_f32_ubyte<k>. R12's bench died with
// "container failed twice" (no compile/test diagnostics); kernel audit found
// no replay hazard (all kernels idempotent), no OOB, no hang path. The
// builtin is the sole untested construct -> eliminated.
//
// Strategy (int8 table, per-channel scale; gather bytes halved):
//  - Evidence: R10 (+38us when gathers lose cache tier), R11 (store policy
//    neutral), R5 (L2 footprint null) => embed is dominated by the 1.02 GB
//    corner-gather stream served from L2/L3. At bf16 the 8x128B lines/point
//    are irreducible; int8 halves bytes AND x-adjacent corner rows share a
//    128 B line.
//  - amax_k: per-channel amax -> scale[e] = amax/127 (256 B).
//  - transpose_quant_k: [E,S] fp32 -> [S,E] u8, q = rn(v/s)+128 in [1,255].
//  - embed_q_k: 8 lanes/point, lane owns 8 channels = 8 B/corner (uint2).
//    Accumulates raw ubytes + sumw; epilogue: out_j = s_j*(acc_j - 128*sumw).
//    Max abs err = amax/254 ~= 1.8e-3, same order as passing bf16 (1.95e-3).
//  - Plain (cached) table loads (R10 lesson), NT x loads, R6 shfl epilogue
//    with full-128B-line NT stores.

constexpr int TSZ = 32;
constexpr int S   = TSZ * TSZ * TSZ;  // 32768 spatial cells
constexpr int EMB = 64;               // channels

typedef float floatx4 __attribute__((ext_vector_type(4)));

// ---------------------------------------------------------------------------
// Per-channel amax -> scale. One block per channel; channel data contiguous.
__global__ __launch_bounds__(256) void amax_k(
    const float* __restrict__ tab, float* __restrict__ scale) {
  __shared__ float red[256];
  const int ch = blockIdx.x;
  const int t  = threadIdx.x;
  float m = 0.f;
  for (int i = 0; i < S / 256; ++i)
    m = fmaxf(m, fabsf(tab[(size_t)ch * S + t + 256 * i]));
  red[t] = m;
  __syncthreads();
  for (int off = 128; off > 0; off >>= 1) {
    if (t < off) red[t] = fmaxf(red[t], red[t + off]);
    __syncthreads();
  }
  if (t == 0) scale[ch] = fmaxf(red[0], 1e-30f) * (1.0f / 127.0f);
}

// ---------------------------------------------------------------------------
// Transpose [EMB, S] fp32 -> [S, EMB] u8 (biased int8) via 64x64 LDS tiles.
__global__ __launch_bounds__(256) void transpose_quant_k(
    const float* __restrict__ tab, const float* __restrict__ scale,
    unsigned char* __restrict__ tabQ) {
  __shared__ float tile[EMB][EMB + 1];
  const int s_base = blockIdx.x * 64;
  const int t  = threadIdx.x;
  const int c0 = t & 63;   // inner index
  const int r0 = t >> 6;   // 0..3
#pragma unroll
  for (int i = 0; i < 16; ++i) {
    const int e = r0 + 4 * i;
    tile[e][c0] = tab[(size_t)e * S + (s_base + c0)];  // coalesced read
  }
  __syncthreads();
  const float rs = 1.0f / scale[c0];  // c0 = output channel for this thread
#pragma unroll
  for (int i = 0; i < 16; ++i) {
    const int s = r0 + 4 * i;
    const int q = __float2int_rn(tile[c0][s] * rs) + 128;  // [1,255]
    tabQ[(size_t)(s_base + s) * EMB + c0] = (unsigned char)q;
  }
}

// ---------------------------------------------------------------------------
// Main kernel: 8 threads per point, each owns 8 channels (8 B per corner).
__global__ __launch_bounds__(256) void embed_q_k(
    const float* __restrict__ x, const unsigned char* __restrict__ tabQ,
    const float* __restrict__ scale, float* __restrict__ out, int n) {
  const int gid = blockIdx.x * 256 + threadIdx.x;
  const int pt  = gid >> 3;
  if (pt >= n) return;
  const int c8 = gid & 7;  // channel octet

  const float gx = fminf(fmaxf(__builtin_nontemporal_load(&x[3 * pt + 0]), -1.f), 1.f);
  const float gy = fminf(fmaxf(__builtin_nontemporal_load(&x[3 * pt + 1]), -1.f), 1.f);
  const float gz = fminf(fmaxf(__builtin_nontemporal_load(&x[3 * pt + 2]), -1.f), 1.f);
  const float px = ((gx + 1.f) * 32.f - 1.f) * 0.5f;
  const float py = ((gy + 1.f) * 32.f - 1.f) * 0.5f;
  const float pz = ((gz + 1.f) * 32.f - 1.f) * 0.5f;

  const float fxf = floorf(px), fyf = floorf(py), fzf = floorf(pz);
  const int ix0 = (int)fxf, iy0 = (int)fyf, iz0 = (int)fzf;
  const float fx = px - fxf, fy = py - fyf, fz = pz - fzf;

  // zeros padding folded into per-axis weights.
  float wxe[2], wye[2], wze[2];
  int   ixc[2], iyc[2], izc[2];
  wxe[0] = (ix0 >= 0)      ? (1.f - fx) : 0.f;
  wxe[1] = (ix0 + 1 < TSZ) ? fx         : 0.f;
  ixc[0] = max(ix0, 0);
  ixc[1] = min(ix0 + 1, TSZ - 1);
  wye[0] = (iy0 >= 0)      ? (1.f - fy) : 0.f;
  wye[1] = (iy0 + 1 < TSZ) ? fy         : 0.f;
  iyc[0] = max(iy0, 0);
  iyc[1] = min(iy0 + 1, TSZ - 1);
  wze[0] = (iz0 >= 0)      ? (1.f - fz) : 0.f;
  wze[1] = (iz0 + 1 < TSZ) ? fz         : 0.f;
  izc[0] = max(iz0, 0);
  izc[1] = min(iz0 + 1, TSZ - 1);

  float a0 = 0.f, a1 = 0.f, a2 = 0.f, a3 = 0.f;
  float a4 = 0.f, a5 = 0.f, a6 = 0.f, a7 = 0.f;
  float sumw = 0.f;

#pragma unroll
  for (int dz = 0; dz < 2; ++dz) {
    const int zb = izc[dz] * (TSZ * TSZ);
#pragma unroll
    for (int dy = 0; dy < 2; ++dy) {
      const int   zyb = zb + iyc[dy] * TSZ;
      const float wzy = wze[dz] * wye[dy];
#pragma unroll
      for (int dx = 0; dx < 2; ++dx) {
        const float w   = wzy * wxe[dx];
        const int   lin = zyb + ixc[dx];
        const uint2 q   = *(const uint2*)(tabQ + (size_t)lin * EMB + c8 * 8);
        sumw += w;
        // (float)((q >> 8k) & 0xFF) pattern-matches to v_cvt_f32_ubyte<k>.
        a0 = fmaf(w, (float)(q.x & 0xFFu),         a0);
        a1 = fmaf(w, (float)((q.x >> 8)  & 0xFFu), a1);
        a2 = fmaf(w, (float)((q.x >> 16) & 0xFFu), a2);
        a3 = fmaf(w, (float)((q.x >> 24) & 0xFFu), a3);
        a4 = fmaf(w, (float)(q.y & 0xFFu),         a4);
        a5 = fmaf(w, (float)((q.y >> 8)  & 0xFFu), a5);
        a6 = fmaf(w, (float)((q.y >> 16) & 0xFFu), a6);
        a7 = fmaf(w, (float)((q.y >> 24) & 0xFFu), a7);
      }
    }
  }

  // Dequant: out_j = s_j * (acc_j - 128*sumw).
  const float m128 = 128.0f * sumw;
  const floatx4 sA = *(const floatx4*)(scale + c8 * 8);
  const floatx4 sB = *(const floatx4*)(scale + c8 * 8 + 4);
  const float accv[8] = {sA.x * (a0 - m128), sA.y * (a1 - m128),
                         sA.z * (a2 - m128), sA.w * (a3 - m128),
                         sB.x * (a4 - m128), sB.y * (a5 - m128),
                         sB.z * (a6 - m128), sB.w * (a7 - m128)};

  // Epilogue (R6): redistribute so each NT store writes a contiguous 128 B
  // line per point.
  const int lane = threadIdx.x & 63;
  const int grp  = lane & ~7;
  const int src1 = grp + (c8 >> 1);
  const int src2 = grp + 4 + (c8 >> 1);
  const bool hi  = (c8 & 1) != 0;
  float o0[4], o1[4];
#pragma unroll
  for (int j = 0; j < 4; ++j) {
    const float aj = __shfl(accv[j],     src1, 64);
    const float bj = __shfl(accv[4 + j], src1, 64);
    o0[j] = hi ? bj : aj;
    const float cj = __shfl(accv[j],     src2, 64);
    const float dj = __shfl(accv[4 + j], src2, 64);
    o1[j] = hi ? dj : cj;
  }
  const floatx4 s0 = {o0[0], o0[1], o0[2], o0[3]};
  const floatx4 s1 = {o1[0], o1[1], o1[2], o1[3]};
  float* rowp = out + (size_t)pt * EMB;
  __builtin_nontemporal_store(s0, (floatx4*)(rowp + c8 * 4));       // [0,128)
  __builtin_nontemporal_store(s1, (floatx4*)(rowp + 32 + c8 * 4));  // [128,256)
}

// ---------------------------------------------------------------------------
// Fallback (workspace too small): 1 thread per (point, channel), fp32 table.
__global__ __launch_bounds__(256) void embed_fallback_k(
    const float* __restrict__ x, const float* __restrict__ tab,
    float* __restrict__ out, int n) {
  const int gid = blockIdx.x * 256 + threadIdx.x;
  const int pt  = gid >> 6;
  if (pt >= n) return;
  const int e = gid & 63;

  const float gx = fminf(fmaxf(x[3 * pt + 0], -1.f), 1.f);
  const float gy = fminf(fmaxf(x[3 * pt + 1], -1.f), 1.f);
  const float gz = fminf(fmaxf(x[3 * pt + 2], -1.f), 1.f);
  const float px = ((gx + 1.f) * 32.f - 1.f) * 0.5f;
  const float py = ((gy + 1.f) * 32.f - 1.f) * 0.5f;
  const float pz = ((gz + 1.f) * 32.f - 1.f) * 0.5f;

  const float fxf = floorf(px), fyf = floorf(py), fzf = floorf(pz);
  const int ix0 = (int)fxf, iy0 = (int)fyf, iz0 = (int)fzf;
  const float fx = px - fxf, fy = py - fyf, fz = pz - fzf;
  const float wx[2] = {1.f - fx, fx};
  const float wy[2] = {1.f - fy, fy};
  const float wz[2] = {1.f - fz, fz};

  float acc = 0.f;
#pragma unroll
  for (int dz = 0; dz < 2; ++dz) {
    const int  iz  = iz0 + dz;
    const bool bz  = (unsigned)iz < (unsigned)TSZ;
    const int  izc = min(max(iz, 0), TSZ - 1);
#pragma unroll
    for (int dy = 0; dy < 2; ++dy) {
      const int  iy  = iy0 + dy;
      const bool by  = (unsigned)iy < (unsigned)TSZ;
      const int  iyc = min(max(iy, 0), TSZ - 1);
#pragma unroll
      for (int dx = 0; dx < 2; ++dx) {
        const int  ix  = ix0 + dx;
        const bool bx  = (unsigned)ix < (unsigned)TSZ;
        const int  ixc = min(max(ix, 0), TSZ - 1);
        float w = wz[dz] * wy[dy] * wx[dx];
        w = (bx && by && bz) ? w : 0.f;
        const int lin = (izc * TSZ + iyc) * TSZ + ixc;
        acc = fmaf(w, tab[(size_t)e * S + lin], acc);
      }
    }
  }
  out[(size_t)pt * EMB + e] = acc;
}

// ---------------------------------------------------------------------------
extern "C" void kernel_launch(void* const* d_in, const int* in_sizes, int n_in,
                              void* d_out, int out_size, void* d_ws,
                              size_t ws_size, hipStream_t stream) {
  const float* x   = (const float*)d_in[0];
  const float* tab = (const float*)d_in[1];
  float*       out = (float*)d_out;
  const int n = in_sizes[0] / 3;

  // ws layout: [scale: 64 f32, padded to 256 B][tabQ: S*64 u8 = 2 MiB]
  const size_t off_tabq = 256;
  const size_t need = off_tabq + (size_t)S * EMB;  // ~2 MiB
  if (ws_size >= need) {
    float*         scale = (float*)d_ws;
    unsigned char* tabQ  = (unsigned char*)d_ws + off_tabq;
    amax_k<<<EMB, 256, 0, stream>>>(tab, scale);
    transpose_quant_k<<<S / 64, 256, 0, stream>>>(tab, scale, tabQ);
    const int total  = n * 8;  // 8 threads per point
    const int blocks = (total + 255) / 256;
    embed_q_k<<<blocks, 256, 0, stream>>>(x, tabQ, scale, out, n);
  } else {
    const int total  = n * EMB;
    const int blocks = (total + 255) / 256;
    embed_fallback_k<<<blocks, 256, 0, stream>>>(x, tab, out, n);
  }
}

// Round 10
// 315.819 us; speedup vs baseline: 1.0664x; 1.0664x over previous
//
#include <hip/hip_runtime.h>

// TableEmbed3D: trilinear grid_sample of a [64, 32,32,32] fp32 table at 1e6
// points, align_corners=False, padding_mode='zeros'.
//
// R14 strategy (= R6/R11 bf16 base + zero-weight corner SKIP):
//  - Evidence chain: R5 (L2 footprint null), R10 (cache-tier sensitive),
//    R11 (store policy null), R13 (int8 byte-halving null-to-negative) =>
//    embed is bound by scattered line-transaction COUNT (8e6 x 128 B line
//    requests, ~8-10 cy L1/TA occupancy each), not bytes.
//  - Input is N(0,1) clipped to [-1,1]: 31.7% of coordinates clip -> land on
//    a face cell where one axis weight is EXACTLY 0 -> 4 of 8 corner weights
//    are 0. E[live corners] = (2-0.317)^3 ~= 4.77 of 8.
//  - NEW: hierarchical zero-weight guards (z-plane / zy-row / corner). All 8
//    lanes of a point share the weight -> exec-masked load issues no
//    transaction for skipped points. ~40% fewer gather transactions.
//  - Everything else identical to R6: table [S][64] bf16 (4 MiB) in d_ws;
//    8 lanes/point, 16 B dense gather per corner; shfl epilogue, full-128B
//    NT stores; NT x loads; packed v_pk_fma_f32.

constexpr int TSZ = 32;
constexpr int S   = TSZ * TSZ * TSZ;  // 32768 spatial cells
constexpr int EMB = 64;               // channels

typedef float floatx4 __attribute__((ext_vector_type(4)));
typedef float f32x2   __attribute__((ext_vector_type(2)));

__device__ __forceinline__ unsigned short f32_to_bf16_rne(float f) {
  unsigned int u = __float_as_uint(f);
  unsigned int lsb = (u >> 16) & 1u;
  u += 0x7FFFu + lsb;  // round to nearest even
  return (unsigned short)(u >> 16);
}

// ---------------------------------------------------------------------------
// Transpose [EMB, S] fp32 -> [S, EMB] bf16 via 64x64 LDS tiles (+1 pad).
__global__ __launch_bounds__(256) void transpose_table_k(
    const float* __restrict__ tab, unsigned short* __restrict__ tabT) {
  __shared__ float tile[EMB][EMB + 1];
  const int s_base = blockIdx.x * 64;
  const int t  = threadIdx.x;
  const int c0 = t & 63;   // inner (coalesced) index
  const int r0 = t >> 6;   // 0..3
#pragma unroll
  for (int i = 0; i < 16; ++i) {
    const int e = r0 + 4 * i;
    tile[e][c0] = tab[(size_t)e * S + (s_base + c0)];  // coalesced read
  }
  __syncthreads();
#pragma unroll
  for (int i = 0; i < 16; ++i) {
    const int s = r0 + 4 * i;
    tabT[(size_t)(s_base + s) * EMB + c0] = f32_to_bf16_rne(tile[c0][s]);
  }
}

// ---------------------------------------------------------------------------
// Main kernel: 8 threads per point, each thread computes 8 channels.
// tabT viewed as uint4* : row lin occupies elements [lin*8 .. lin*8+7];
// lane c8 reads element lin*8 + c8 (16 B = 8 bf16 channels).
__global__ __launch_bounds__(256) void embed_k(
    const float* __restrict__ x, const uint4* __restrict__ tabT,
    float* __restrict__ out, int n) {
  const int gid = blockIdx.x * 256 + threadIdx.x;
  const int pt  = gid >> 3;
  if (pt >= n) return;
  const int c8 = gid & 7;  // channel octet (8 channels each)

  // clip to [-1,1] then align_corners=False pixel mapping:
  // pix = ((g + 1) * 32 - 1) / 2
  const float gx = fminf(fmaxf(__builtin_nontemporal_load(&x[3 * pt + 0]), -1.f), 1.f);
  const float gy = fminf(fmaxf(__builtin_nontemporal_load(&x[3 * pt + 1]), -1.f), 1.f);
  const float gz = fminf(fmaxf(__builtin_nontemporal_load(&x[3 * pt + 2]), -1.f), 1.f);
  const float px = ((gx + 1.f) * 32.f - 1.f) * 0.5f;
  const float py = ((gy + 1.f) * 32.f - 1.f) * 0.5f;
  const float pz = ((gz + 1.f) * 32.f - 1.f) * 0.5f;

  const float fxf = floorf(px), fyf = floorf(py), fzf = floorf(pz);
  const int ix0 = (int)fxf, iy0 = (int)fyf, iz0 = (int)fzf;
  const float fx = px - fxf, fy = py - fyf, fz = pz - fzf;

  // zeros padding folded into per-axis weights: w*inb =
  // (wz*bz)*(wy*by)*(wx*bx). Clamped index is irrelevant when weight==0.
  float wxe[2], wye[2], wze[2];
  int   ixc[2], iyc[2], izc[2];
  wxe[0] = (ix0 >= 0)      ? (1.f - fx) : 0.f;
  wxe[1] = (ix0 + 1 < TSZ) ? fx         : 0.f;
  ixc[0] = max(ix0, 0);
  ixc[1] = min(ix0 + 1, TSZ - 1);
  wye[0] = (iy0 >= 0)      ? (1.f - fy) : 0.f;
  wye[1] = (iy0 + 1 < TSZ) ? fy         : 0.f;
  iyc[0] = max(iy0, 0);
  iyc[1] = min(iy0 + 1, TSZ - 1);
  wze[0] = (iz0 >= 0)      ? (1.f - fz) : 0.f;
  wze[1] = (iz0 + 1 < TSZ) ? fz         : 0.f;
  izc[0] = max(iz0, 0);
  izc[1] = min(iz0 + 1, TSZ - 1);

  f32x2 a01 = {0.f, 0.f}, a23 = {0.f, 0.f}, a45 = {0.f, 0.f}, a67 = {0.f, 0.f};

#pragma unroll
  for (int dz = 0; dz < 2; ++dz) {
    const float wz_ = wze[dz];
    if (wz_ == 0.f) continue;  // clipped z-face: skip 4 corners (no loads)
    const int zb = izc[dz] * (TSZ * TSZ);
#pragma unroll
    for (int dy = 0; dy < 2; ++dy) {
      const float wzy = wz_ * wye[dy];
      if (wzy == 0.f) continue;  // clipped y-face: skip 2 corners
      const int zyb = zb + iyc[dy] * TSZ;
#pragma unroll
      for (int dx = 0; dx < 2; ++dx) {
        const float w = wzy * wxe[dx];
        if (w == 0.f) continue;  // clipped x-face: skip this corner's load
        const int   lin = zyb + ixc[dx];
        const uint4 q   = tabT[lin * 8 + c8];
        const f32x2 w2  = {w, w};
        const f32x2 v01 = {__uint_as_float(q.x << 16),
                           __uint_as_float(q.x & 0xFFFF0000u)};
        const f32x2 v23 = {__uint_as_float(q.y << 16),
                           __uint_as_float(q.y & 0xFFFF0000u)};
        const f32x2 v45 = {__uint_as_float(q.z << 16),
                           __uint_as_float(q.z & 0xFFFF0000u)};
        const f32x2 v67 = {__uint_as_float(q.w << 16),
                           __uint_as_float(q.w & 0xFFFF0000u)};
        a01 = __builtin_elementwise_fma(v01, w2, a01);
        a23 = __builtin_elementwise_fma(v23, w2, a23);
        a45 = __builtin_elementwise_fma(v45, w2, a45);
        a67 = __builtin_elementwise_fma(v67, w2, a67);
      }
    }
  }

  // -------------------------------------------------------------------------
  // Epilogue (R6): redistribute so each NT store instruction writes a
  // CONTIGUOUS 128 B per point.
  const float accv[8] = {a01.x, a01.y, a23.x, a23.y, a45.x, a45.y, a67.x, a67.y};
  const int lane = threadIdx.x & 63;
  const int grp  = lane & ~7;            // 8-lane point group within the wave
  const int src1 = grp + (c8 >> 1);
  const int src2 = grp + 4 + (c8 >> 1);
  const bool hi  = (c8 & 1) != 0;
  float o0[4], o1[4];
#pragma unroll
  for (int j = 0; j < 4; ++j) {
    const float aj = __shfl(accv[j],     src1, 64);
    const float bj = __shfl(accv[4 + j], src1, 64);
    o0[j] = hi ? bj : aj;
    const float cj = __shfl(accv[j],     src2, 64);
    const float dj = __shfl(accv[4 + j], src2, 64);
    o1[j] = hi ? dj : cj;
  }
  const floatx4 s0 = {o0[0], o0[1], o0[2], o0[3]};
  const floatx4 s1 = {o1[0], o1[1], o1[2], o1[3]};
  float* rowp = out + (size_t)pt * EMB;  // 256 B output row
  __builtin_nontemporal_store(s0, (floatx4*)(rowp + c8 * 4));       // [0,128)
  __builtin_nontemporal_store(s1, (floatx4*)(rowp + 32 + c8 * 4));  // [128,256)
}

// ---------------------------------------------------------------------------
// Fallback (workspace too small): 1 thread per (point, channel), reads the
// original [E, S] fp32 layout. Slow but correct.
__global__ __launch_bounds__(256) void embed_fallback_k(
    const float* __restrict__ x, const float* __restrict__ tab,
    float* __restrict__ out, int n) {
  const int gid = blockIdx.x * 256 + threadIdx.x;
  const int pt  = gid >> 6;
  if (pt >= n) return;
  const int e = gid & 63;

  const float gx = fminf(fmaxf(x[3 * pt + 0], -1.f), 1.f);
  const float gy = fminf(fmaxf(x[3 * pt + 1], -1.f), 1.f);
  const float gz = fminf(fmaxf(x[3 * pt + 2], -1.f), 1.f);
  const float px = ((gx + 1.f) * 32.f - 1.f) * 0.5f;
  const float py = ((gy + 1.f) * 32.f - 1.f) * 0.5f;
  const float pz = ((gz + 1.f) * 32.f - 1.f) * 0.5f;

  const float fxf = floorf(px), fyf = floorf(py), fzf = floorf(pz);
  const int ix0 = (int)fxf, iy0 = (int)fyf, iz0 = (int)fzf;
  const float fx = px - fxf, fy = py - fyf, fz = pz - fzf;
  const float wx[2] = {1.f - fx, fx};
  const float wy[2] = {1.f - fy, fy};
  const float wz[2] = {1.f - fz, fz};

  float acc = 0.f;
#pragma unroll
  for (int dz = 0; dz < 2; ++dz) {
    const int  iz  = iz0 + dz;
    const bool bz  = (unsigned)iz < (unsigned)TSZ;
    const int  izc = min(max(iz, 0), TSZ - 1);
#pragma unroll
    for (int dy = 0; dy < 2; ++dy) {
      const int  iy  = iy0 + dy;
      const bool by  = (unsigned)iy < (unsigned)TSZ;
      const int  iyc = min(max(iy, 0), TSZ - 1);
#pragma unroll
      for (int dx = 0; dx < 2; ++dx) {
        const int  ix  = ix0 + dx;
        const bool bx  = (unsigned)ix < (unsigned)TSZ;
        const int  ixc = min(max(ix, 0), TSZ - 1);
        float w = wz[dz] * wy[dy] * wx[dx];
        w = (bx && by && bz) ? w : 0.f;
        const int lin = (izc * TSZ + iyc) * TSZ + ixc;
        acc = fmaf(w, tab[(size_t)e * S + lin], acc);
      }
    }
  }
  out[(size_t)pt * EMB + e] = acc;
}

// ---------------------------------------------------------------------------
extern "C" void kernel_launch(void* const* d_in, const int* in_sizes, int n_in,
                              void* d_out, int out_size, void* d_ws,
                              size_t ws_size, hipStream_t stream) {
  const float* x   = (const float*)d_in[0];
  const float* tab = (const float*)d_in[1];
  float*       out = (float*)d_out;
  const int n = in_sizes[0] / 3;

  const size_t need = (size_t)S * EMB * sizeof(unsigned short);  // 4 MiB
  if (ws_size >= need) {
    unsigned short* tabT = (unsigned short*)d_ws;
    transpose_table_k<<<S / 64, 256, 0, stream>>>(tab, tabT);
    const int total  = n * 8;  // 8 threads per point
    const int blocks = (total + 255) / 256;
    embed_k<<<blocks, 256, 0, stream>>>(x, (const uint4*)tabT, out, n);
  } else {
    const int total  = n * EMB;
    const int blocks = (total + 255) / 256;
    embed_fallback_k<<<blocks, 256, 0, stream>>>(x, tab, out, n);
  }
}